// Round 15
// baseline (225.531 us; speedup 1.0000x reference)
//
#include <hip/hip_runtime.h>
#include <math.h>

// Problem constants: B=4, C=64, H=W=64 -> HW=4096
#define BATCH 4
#define CH 64
#define HW 4096
#define LOG2E 1.4426950408889634f

typedef __attribute__((ext_vector_type(8))) short short8;
typedef __attribute__((ext_vector_type(4))) float f32x4;
typedef __attribute__((ext_vector_type(4))) float float4v;
typedef __attribute__((ext_vector_type(4))) unsigned int uint4v;

#define MFMA(a, b, c) __builtin_amdgcn_mfma_f32_16x16x32_bf16(a, b, c, 0, 0, 0)

// 2^x. MUST go through the builtin (or libm), NOT raw asm: v_exp_f32 is a
// TRANS op and the compiler's hazard recognizer can't see inside an asm blob
// (R12 failed with absmax 0.84 from exactly that missing wait-state).
__device__ __forceinline__ float exp2v(float x) {
#if __has_builtin(__builtin_amdgcn_exp2f)
    return __builtin_amdgcn_exp2f(x);
#else
    return exp2f(x);
#endif
}
// pack 2 floats -> bf16 hi-word pair + exact-residual lo-word pair.
__device__ __forceinline__ void cvtpk2(float a, float b, unsigned &h, unsigned &l) {
    unsigned hv;
    asm("v_cvt_pk_bf16_f32 %0, %1, %2" : "=v"(hv) : "v"(a), "v"(b));
    float ra = a - __builtin_bit_cast(float, hv << 16);
    float rb = b - __builtin_bit_cast(float, hv & 0xffff0000u);
    unsigned lv;
    asm("v_cvt_pk_bf16_f32 %0, %1, %2" : "=v"(lv) : "v"(ra), "v"(rb));
    h = hv; l = lv;
}
// async global->LDS, 16B per lane; lds base must be wave-uniform
__device__ __forceinline__ void gld16(const short* g, short* l) {
    __builtin_amdgcn_global_load_lds(
        (const __attribute__((address_space(1))) unsigned int*)g,
        (__attribute__((address_space(3))) unsigned int*)l, 16, 0, 0);
}

// ---------------------------------------------------------------------------
// convm: 1x1 convs via 3-term split-bf16 MFMA; B-frags built inline from X.
// mode: 0 W_low->XLOW fp32 + PA | 1 W_val->PV (sigma-permuted k)
//       2 W_mid->XMID | 3 W_lat->XL2 | 4 W_high->PB (scaled by LOG2E).
// (R13-proven version.)
// ---------------------------------------------------------------------------
__global__ __launch_bounds__(256) void convm(
    const float* __restrict__ x, const float* __restrict__ xl,
    const float* __restrict__ Wlow, const float* __restrict__ blow,
    const float* __restrict__ Wval, const float* __restrict__ bval,
    const float* __restrict__ Wmid, const float* __restrict__ bmid,
    const float* __restrict__ Wlat, const float* __restrict__ blat,
    const float* __restrict__ Whigh, const float* __restrict__ bhigh,
    float* __restrict__ XLOW, float* __restrict__ XMID, float* __restrict__ XL2,
    short* __restrict__ PAh, short* __restrict__ PAl,
    short* __restrict__ PBh, short* __restrict__ PBl,
    short* __restrict__ PVh, short* __restrict__ PVl)
{
    int mode = blockIdx.z, b = blockIdx.y, bx = blockIdx.x;
    const float* W; const float* bias; const float* X;
    switch (mode) {
        case 0:  W = Wlow;  bias = blow;  X = x;  break;
        case 1:  W = Wval;  bias = bval;  X = x;  break;
        case 2:  W = Wmid;  bias = bmid;  X = x;  break;
        case 3:  W = Wlat;  bias = blat;  X = xl; break;
        default: W = Whigh; bias = bhigh; X = xl; break;
    }
    int t = threadIdx.x, wv = t >> 6, ln = t & 63;
    int row = ln & 15, g = ln >> 4;

    // W A-frags (hi/lo)
    short8 Wh[4][2], Wlo[4][2];
    #pragma unroll
    for (int ot = 0; ot < 4; ot++)
        #pragma unroll
        for (int kt = 0; kt < 2; kt++) {
            const float* wp = W + (ot * 16 + row) * 64 + kt * 32 + g * 8;
            uint4v hw, lw;
            #pragma unroll
            for (int k2 = 0; k2 < 4; k2++) {
                unsigned h, l;
                cvtpk2(wp[2 * k2], wp[2 * k2 + 1], h, l);
                hw[k2] = h; lw[k2] = l;
            }
            Wh[ot][kt] = __builtin_bit_cast(short8, hw);
            Wlo[ot][kt] = __builtin_bit_cast(short8, lw);
        }

    // X B-frags built inline: value = X[c = kt*32+g*8+j][nt*16+row]
    int nt = bx * 4 + wv;
    short8 Bh[2], Bl[2];
    #pragma unroll
    for (int kt = 0; kt < 2; kt++) {
        float v[8];
        #pragma unroll
        for (int j = 0; j < 8; j++)
            v[j] = X[(size_t)(b * 64 + kt * 32 + g * 8 + j) * HW + nt * 16 + row];
        uint4v hw, lw;
        #pragma unroll
        for (int k2 = 0; k2 < 4; k2++) {
            unsigned h, l;
            cvtpk2(v[2 * k2], v[2 * k2 + 1], h, l);
            hw[k2] = h; lw[k2] = l;
        }
        Bh[kt] = __builtin_bit_cast(short8, hw);
        Bl[kt] = __builtin_bit_cast(short8, lw);
    }

    f32x4 acc[4];
    #pragma unroll
    for (int ot = 0; ot < 4; ot++) {
        #pragma unroll
        for (int r = 0; r < 4; r++) acc[ot][r] = bias[ot * 16 + g * 4 + r];
    }
    #pragma unroll
    for (int ot = 0; ot < 4; ot++)
        #pragma unroll
        for (int kt = 0; kt < 2; kt++) {
            acc[ot] = MFMA(Wh[ot][kt], Bh[kt], acc[ot]);
            acc[ot] = MFMA(Wh[ot][kt], Bl[kt], acc[ot]);
            acc[ot] = MFMA(Wlo[ot][kt], Bh[kt], acc[ot]);
        }

    __shared__ float Ld[64][65];
    #pragma unroll
    for (int ot = 0; ot < 4; ot++)
        #pragma unroll
        for (int r = 0; r < 4; r++)
            Ld[wv * 16 + (ln & 15)][ot * 16 + g * 4 + r] = acc[ot][r];
    __syncthreads();

    int n0 = bx * 64;
    if (mode == 0 || mode == 2 || mode == 3) {
        float* outp = (mode == 0) ? XLOW : (mode == 2) ? XMID : XL2;
        int n = t >> 2, o0 = (t & 3) * 16;
        float vout[16];
        #pragma unroll
        for (int k = 0; k < 16; k++) vout[k] = Ld[n][o0 + k];
        float* gp = outp + ((size_t)b * HW + n0 + n) * 64 + o0;
        #pragma unroll
        for (int k = 0; k < 4; k++)
            *(float4v*)(gp + k * 4) = *(float4v*)(vout + k * 4);
    }
    if (mode == 0 || mode == 4) {
        // PA (rows=n) or PB (cols=m) — same transform. PB scaled by LOG2E so
        // S' = S*log2(e) and exp(S) = 2^(S') via v_exp_f32 downstream.
        short* Ph = (mode == 0) ? PAh : PBh;
        short* Pl = (mode == 0) ? PAl : PBl;
        float scale = (mode == 4) ? LOG2E : 1.0f;
        #pragma unroll
        for (int kt = 0; kt < 2; kt++) {
            uint4v hw, lw;
            #pragma unroll
            for (int k2 = 0; k2 < 4; k2++) {
                unsigned h, l;
                cvtpk2(Ld[wv * 16 + (ln & 15)][kt * 32 + g * 8 + 2 * k2] * scale,
                       Ld[wv * 16 + (ln & 15)][kt * 32 + g * 8 + 2 * k2 + 1] * scale, h, l);
                hw[k2] = h; lw[k2] = l;
            }
            size_t blob = (((size_t)b * 256 + bx * 4 + wv) * 2 + kt) * 512 + (size_t)ln * 8;
            *(uint4v*)(Ph + blob) = hw;
            *(uint4v*)(Pl + blob) = lw;
        }
    }
    if (mode == 1) {
        // PV: B-frag, k = m with sigma-permutation: k-slot (kt, g, j) holds
        //   m_local = (kt*2 + (j>>2))*16 + g*4 + (j&3)
        int ktm_l = wv >> 1;
        int ct0 = (wv & 1) * 2;
        #pragma unroll
        for (int cc = 0; cc < 2; cc++) {
            int ct = ct0 + cc;
            int c = ct * 16 + (ln & 15);
            float v[8];
            #pragma unroll
            for (int j = 0; j < 8; j++)
                v[j] = Ld[(ktm_l * 2 + (j >> 2)) * 16 + g * 4 + (j & 3)][c];
            uint4v hw, lw;
            #pragma unroll
            for (int k2 = 0; k2 < 4; k2++) {
                unsigned h, l;
                cvtpk2(v[2 * k2], v[2 * k2 + 1], h, l);
                hw[k2] = h; lw[k2] = l;
            }
            size_t blob = (((size_t)b * 128 + bx * 2 + ktm_l) * 4 + ct) * 512 + (size_t)ln * 8;
            *(uint4v*)(PVh + blob) = hw;
            *(uint4v*)(PVl + blob) = lw;
        }
    }
}

// ---------------------------------------------------------------------------
// zpass2: Z partials; XCD swizzle; deferred cross-lane reduce; exp2 (PB is
// pre-scaled by LOG2E). (R13-proven.)
// ---------------------------------------------------------------------------
__global__ __launch_bounds__(256) void zpass2(
    const short* __restrict__ PAh, const short* __restrict__ PAl,
    const short* __restrict__ PBh, const short* __restrict__ PBl,
    float* __restrict__ Zp)
{
    int bid = blockIdx.x;
    int sw = (bid & 7) * 128 + (bid >> 3);       // XCD-bijective swizzle
    int mchunk = sw & 63, nc = (sw >> 6) & 3, b = sw >> 8;
    int t = threadIdx.x, wv = t >> 6, ln = t & 63;
    short8 bh[4][2], bl[4][2];
    #pragma unroll
    for (int msub = 0; msub < 4; msub++)
        #pragma unroll
        for (int kt = 0; kt < 2; kt++) {
            size_t o = ((size_t)(b * 256 + mchunk * 4 + msub) * 2 + kt) * 512 + ln * 8;
            bh[msub][kt] = *(const short8*)(PBh + o);
            bl[msub][kt] = *(const short8*)(PBl + o);
        }
    float zacc[4] = {0.f, 0.f, 0.f, 0.f};
    for (int s = 0; s < 16; s++) {
        int nt = nc * 64 + s * 4 + wv;
        size_t ab = ((size_t)(b * 256 + nt) * 2) * 512 + ln * 8;
        short8 ah0 = *(const short8*)(PAh + ab);
        short8 ah1 = *(const short8*)(PAh + ab + 512);
        short8 al0 = *(const short8*)(PAl + ab);
        short8 al1 = *(const short8*)(PAl + ab + 512);
        #pragma unroll
        for (int msub = 0; msub < 4; msub++) {
            f32x4 acc = {0.f, 0.f, 0.f, 0.f};
            acc = MFMA(ah0, bh[msub][0], acc);
            acc = MFMA(ah1, bh[msub][1], acc);
            acc = MFMA(ah0, bl[msub][0], acc);
            acc = MFMA(ah1, bl[msub][1], acc);
            acc = MFMA(al0, bh[msub][0], acc);
            acc = MFMA(al1, bh[msub][1], acc);
            zacc[msub] += exp2v(acc[0]) + exp2v(acc[1]) + exp2v(acc[2]) + exp2v(acc[3]);
        }
    }
    #pragma unroll
    for (int msub = 0; msub < 4; msub++) {
        zacc[msub] += __shfl_xor(zacc[msub], 16, 64);
        zacc[msub] += __shfl_xor(zacc[msub], 32, 64);
    }
    __shared__ float sZ[4][64];
    if (ln < 16) {
        #pragma unroll
        for (int msub = 0; msub < 4; msub++) sZ[wv][msub * 16 + ln] = zacc[msub];
    }
    __syncthreads();
    if (t < 64) {
        float z = sZ[0][t] + sZ[1][t] + sZ[2][t] + sZ[3][t];
        Zp[((size_t)(b * 4 + nc)) * 4096 + mchunk * 64 + t] = z;
    }
}

// ---------------------------------------------------------------------------
// epass11: R13 core re-partitioned for max occupancy — 512 thr (8 waves),
// 1 row-tile/wave, same 32-m tiles and 36 KB LDS -> 4 blocks/CU = 32 waves/CU
// (8/SIMD, was 4). Identical math to epass10 (bit-identical results).
// grid (32 nb x nseg x 4 b, XCD-swizzled).
// ---------------------------------------------------------------------------
__global__ __launch_bounds__(512, 8) void epass11(
    const short* __restrict__ PAh, const short* __restrict__ PAl,
    const short* __restrict__ PBh, const short* __restrict__ PBl,
    const short* __restrict__ PVh, const short* __restrict__ PVl,
    const float* __restrict__ Zp, float* __restrict__ Ep, int nseg)
{
    int nwg = 32 * nseg * 4, cpx = nwg >> 3;
    int bid = blockIdx.x;
    int sw = (bid & 7) * cpx + (bid >> 3);       // XCD-bijective
    int nb = sw & 31, mseg = (sw >> 5) % nseg, b = sw / (32 * nseg);
    int iters = 128 / nseg;                       // 32-m tiles per segment
    int mper = 4096 / nseg;
    int t = threadIdx.x, wv = t >> 6, ln = t & 63;
    int lnm = ln & 15, lnr = ln >> 4;

    __shared__ __align__(16) short sB[2][2][2048];   // 16 KB [buf][hi/lo]
    __shared__ __align__(16) short sV[2][2][2048];   // 16 KB
    __shared__ __align__(16) float sZi[1024];

    // folded zmerge
    for (int k = t; k < mper; k += 512) {
        int m = mseg * mper + k;
        float z = Zp[((size_t)(b * 4 + 0)) * 4096 + m]
                + Zp[((size_t)(b * 4 + 1)) * 4096 + m]
                + Zp[((size_t)(b * 4 + 2)) * 4096 + m]
                + Zp[((size_t)(b * 4 + 3)) * 4096 + m];
        sZi[k] = 1.f / z;
    }

    // stationary XLOW B-frag: 1 row-tile per wave (block covers 128 n-rows)
    int nt = nb * 8 + wv;
    short8 Lh[2], Ll[2];
    #pragma unroll
    for (int kt = 0; kt < 2; kt++) {
        size_t base = ((size_t)(b * 256 + nt) * 2 + kt) * 512 + ln * 8;
        Lh[kt] = *(const short8*)(PAh + base);
        Ll[kt] = *(const short8*)(PAl + base);
    }

    f32x4 acc_e[4];   // [ct]
    #pragma unroll
    for (int ct = 0; ct < 4; ct++) acc_e[ct] = (f32x4){0.f, 0.f, 0.f, 0.f};

    const int mt00 = mseg * (mper >> 4);
    const int ktm0 = mseg * (mper >> 5);
    // wave wv covers a 2KB slice of the 16KB tile: array a = wv>>1, half = wv&1
    const int arr_ = wv >> 1, half_ = wv & 1;
    #define STAGE(bufi, ii) { \
        size_t pbb = (size_t)b * 262144 + (size_t)(mt00 + (ii) * 2) * 1024; \
        size_t pvb = (size_t)b * 262144 + (size_t)(ktm0 + (ii)) * 2048; \
        const short* gsrc = (arr_ == 0) ? PBh + pbb : (arr_ == 1) ? PBl + pbb \
                          : (arr_ == 2) ? PVh + pvb : PVl + pvb; \
        short* ldst = (arr_ == 0) ? &sB[bufi][0][0] : (arr_ == 1) ? &sB[bufi][1][0] \
                    : (arr_ == 2) ? &sV[bufi][0][0] : &sV[bufi][1][0]; \
        gld16(gsrc + half_ * 1024 + ln * 8,       ldst + half_ * 1024); \
        gld16(gsrc + half_ * 1024 + 512 + ln * 8, ldst + half_ * 1024 + 512); }

    STAGE(0, 0);
    __syncthreads();

    for (int i = 0; i < iters; i++) {
        int cur = i & 1;
        if (i + 1 < iters) STAGE(cur ^ 1, i + 1);

        // ---- S'^T (3-term, swapped operands); w = 2^(S') * Zi
        f32x4 wf[2];   // [ms]
        #pragma unroll
        for (int ms = 0; ms < 2; ms++) {
            const short8 bh0 = *(const short8*)&sB[cur][0][(ms * 2 + 0) * 512 + ln * 8];
            const short8 bh1 = *(const short8*)&sB[cur][0][(ms * 2 + 1) * 512 + ln * 8];
            const short8 bl0 = *(const short8*)&sB[cur][1][(ms * 2 + 0) * 512 + ln * 8];
            const short8 bl1 = *(const short8*)&sB[cur][1][(ms * 2 + 1) * 512 + ln * 8];
            const f32x4 vz = *(const f32x4*)&sZi[i * 32 + ms * 16 + lnr * 4];
            __builtin_amdgcn_s_setprio(1);
            f32x4 acc = {0.f, 0.f, 0.f, 0.f};
            acc = MFMA(bh0, Lh[0], acc);
            acc = MFMA(bh1, Lh[1], acc);
            acc = MFMA(bh0, Ll[0], acc);
            acc = MFMA(bh1, Ll[1], acc);
            acc = MFMA(bl0, Lh[0], acc);
            acc = MFMA(bl1, Lh[1], acc);
            __builtin_amdgcn_s_setprio(0);
            #pragma unroll
            for (int r = 0; r < 4; r++)
                wf[ms][r] = exp2v(acc[r]) * vz[r];
        }
        // ---- pack P A-frag via cvt_pk (sigma: j-slot <- wf[j>>2][j&3])
        short8 pah, pal;
        {
            uint4v hw, lw;
            #pragma unroll
            for (int k2 = 0; k2 < 4; k2++) {
                unsigned h, l;
                cvtpk2(wf[k2 >> 1][2 * (k2 & 1)],
                       wf[k2 >> 1][2 * (k2 & 1) + 1], h, l);
                hw[k2] = h; lw[k2] = l;
            }
            pah = __builtin_bit_cast(short8, hw);
            pal = __builtin_bit_cast(short8, lw);
        }
        // ---- PV (K=32): acc_e += pah*(vh+vl) + pal*vh
        __builtin_amdgcn_s_setprio(1);
        #pragma unroll
        for (int ct = 0; ct < 4; ct++) {
            const short8 vh = *(const short8*)&sV[cur][0][ct * 512 + ln * 8];
            const short8 vl = *(const short8*)&sV[cur][1][ct * 512 + ln * 8];
            acc_e[ct] = MFMA(pah, vh, acc_e[ct]);
            acc_e[ct] = MFMA(pah, vl, acc_e[ct]);
            acc_e[ct] = MFMA(pal, vh, acc_e[ct]);
        }
        __builtin_amdgcn_s_setprio(0);
        __syncthreads();
    }
    #undef STAGE

    // epilogue: fp32 partials Ep[mseg][b][n][c]
    float* ep = Ep + ((size_t)mseg * BATCH + b) * HW * 64;
    int n0 = nt * 16 + lnr * 4;
    #pragma unroll
    for (int ct = 0; ct < 4; ct++) {
        #pragma unroll
        for (int r = 0; r < 4; r++)
            ep[(size_t)(n0 + r) * 64 + ct * 16 + lnm] = acc_e[ct][r];
    }
}

// ---------------------------------------------------------------------------
// econv6<NSEG>: E1 = sum(NSEG partials) + XLOW, then E2 = W_ec*E1 + b_ec.
// ---------------------------------------------------------------------------
template <int NSEG>
__global__ __launch_bounds__(256) void econv6(
    const float* __restrict__ Ep, const float* __restrict__ XLOW,
    const float* __restrict__ W, const float* __restrict__ bias,
    float* __restrict__ E2)
{
    const size_t SEG = (size_t)BATCH * HW * 64;
    int b = blockIdx.y, n0 = blockIdx.x * 64, t = threadIdx.x;
    __shared__ float Wl[64][64];
    __shared__ float El[64][65];
    for (int i = t; i < 4096; i += 256) Wl[i >> 6][i & 63] = W[i];
    for (int q = t; q < 1024; q += 256) {          // q indexes float4 groups
        int nl = q >> 4, c0 = (q & 15) * 4;
        size_t idx = ((size_t)b * HW + n0 + nl) * 64 + c0;
        float4v s = *(const float4v*)(XLOW + idx);
        #pragma unroll
        for (int sg = 0; sg < NSEG; sg++) {
            float4v p = *(const float4v*)(Ep + sg * SEG + idx);
            s.x += p.x; s.y += p.y; s.z += p.z; s.w += p.w;
        }
        El[nl][c0] = s.x; El[nl][c0 + 1] = s.y;
        El[nl][c0 + 2] = s.z; El[nl][c0 + 3] = s.w;
    }
    __syncthreads();
    int nl = t & 63, og = t >> 6;
    for (int k = 0; k < 16; k++) {
        int o = og * 16 + k;
        float a0 = bias[o], a1 = 0.f, a2 = 0.f, a3 = 0.f;
        #pragma unroll
        for (int c = 0; c < 64; c += 4) {
            a0 += Wl[o][c]     * El[nl][c];
            a1 += Wl[o][c + 1] * El[nl][c + 1];
            a2 += Wl[o][c + 2] * El[nl][c + 2];
            a3 += Wl[o][c + 3] * El[nl][c + 3];
        }
        E2[((size_t)b * 64 + o) * HW + n0 + nl] = (a0 + a1) + (a2 + a3);
    }
}

// ---------------------------------------------------------------------------
// tmat: T[b][c][d] = sum_n E2[b][c][n] * XL2[b][n][d]; block 1024 (R13).
// ---------------------------------------------------------------------------
__global__ __launch_bounds__(1024) void tmat(
    const float* __restrict__ E2, const float* __restrict__ XL2, float* __restrict__ T)
{
    int b = blockIdx.y, c = blockIdx.x, t = threadIdx.x;
    int d = t & 63, nl = t >> 6;   // nl 0..15
    const float* e = E2 + ((size_t)b * 64 + c) * HW;
    const float* x2 = XL2 + (size_t)b * HW * 64;
    float a0 = 0.f, a1 = 0.f;
    #pragma unroll 4
    for (int k = 0; k < 256; k += 2) {
        int na = k * 16 + nl, nb2 = na + 16;
        a0 += e[na] * x2[(size_t)na * 64 + d];
        a1 += e[nb2] * x2[(size_t)nb2 * 64 + d];
    }
    __shared__ float red[16][64];
    red[nl][d] = a0 + a1;
    __syncthreads();
    if (t < 64) {
        float s = 0.f;
        #pragma unroll
        for (int j = 0; j < 16; j++) s += red[j][t];
        T[((size_t)b * 64 + c) * 64 + t] = s;
    }
}

// softmax over c for each (b, d)
__global__ __launch_bounds__(64) void softT(
    const float* __restrict__ T, float* __restrict__ Ts)
{
    int d = blockIdx.x, b = blockIdx.y, c = threadIdx.x;
    float v = T[((size_t)b * 64 + c) * 64 + d];
    float M = v;
    #pragma unroll
    for (int o = 32; o > 0; o >>= 1) M = fmaxf(M, __shfl_xor(M, o, 64));
    float ez = __expf(v - M);
    float Z = ez;
    #pragma unroll
    for (int o = 32; o > 0; o >>= 1) Z += __shfl_xor(Z, o, 64);
    Ts[((size_t)b * 64 + c) * 64 + d] = ez / Z;
}

// out[b][d][n] = sum_c XMID[b][n][c] * Ts[b][c][d]
__global__ __launch_bounds__(256) void outk(
    const float* __restrict__ XMID, const float* __restrict__ Ts, float* __restrict__ out)
{
    int b = blockIdx.y, n0 = blockIdx.x * 64, t = threadIdx.x;
    __shared__ float Xm[64][65];
    __shared__ float Tl[64][64];
    for (int i = t; i < 4096; i += 256) {
        int nl = i >> 6, c = i & 63;
        Xm[nl][c] = XMID[((size_t)b * HW + n0 + nl) * 64 + c];
    }
    for (int i = t; i < 4096; i += 256) Tl[i >> 6][i & 63] = Ts[(size_t)b * 4096 + i];
    __syncthreads();
    int nl = t & 63, dg = t >> 6;
    float accs[16];
    #pragma unroll
    for (int k = 0; k < 16; k++) accs[k] = 0.f;
    for (int c = 0; c < 64; c++) {
        float xv = Xm[nl][c];
        #pragma unroll
        for (int k = 0; k < 16; k++) accs[k] += xv * Tl[c][dg * 16 + k];
    }
    #pragma unroll
    for (int k = 0; k < 16; k++) {
        int d = dg * 16 + k;
        out[((size_t)b * 64 + d) * HW + n0 + nl] = accs[k];
    }
}

// ---------------------------------------------------------------------------
extern "C" void kernel_launch(void* const* d_in, const int* in_sizes, int n_in,
                              void* d_out, int out_size, void* d_ws, size_t ws_size,
                              hipStream_t stream)
{
    const float* x_latter = (const float*)d_in[0];
    const float* x        = (const float*)d_in[1];
    const float* W_high = (const float*)d_in[2];  const float* b_high = (const float*)d_in[3];
    const float* W_low  = (const float*)d_in[4];  const float* b_low  = (const float*)d_in[5];
    const float* W_val  = (const float*)d_in[6];  const float* b_val  = (const float*)d_in[7];
    const float* W_ec   = (const float*)d_in[8];  const float* b_ec   = (const float*)d_in[9];
    const float* W_mid  = (const float*)d_in[10]; const float* b_mid  = (const float*)d_in[11];
    const float* W_lat  = (const float*)d_in[12]; const float* b_lat  = (const float*)d_in[13];
    float* outp = (float*)d_out;

    const size_t MAT = (size_t)BATCH * CH * HW;  // 1,048,576 elements

    // ws budget: fixed floats (3 MAT + Zp + T + Ts) + 6 MAT shorts + Ep(nseg MAT)
    const size_t fixed_f = 3 * MAT + (size_t)BATCH * 4 * HW + 2 * (size_t)BATCH * 64 * 64;
    const size_t need8 = (fixed_f + 8 * MAT) * 4 + 6 * MAT * 2;
    int nseg = (ws_size >= need8) ? 8 : 4;

    float* ws = (float*)d_ws;
    size_t off = 0;
    float* XLOW = ws + off; off += MAT;              // [b][n][c]
    float* XMID = ws + off; off += MAT;              // [b][n][c]
    float* XL2  = ws + off; off += MAT;              // [b][n][d]
    float* Zp   = ws + off; off += (size_t)BATCH * 4 * HW;
    float* T    = ws + off; off += (size_t)BATCH * 64 * 64;
    float* Ts   = ws + off; off += (size_t)BATCH * 64 * 64;
    short* sp = (short*)(ws + off);
    short* PAh = sp; sp += MAT;   // packed frags of XLOW (hi)
    short* PAl = sp; sp += MAT;
    short* PBh = sp; sp += MAT;   // packed frags of XLHI (pre-scaled by LOG2E)
    short* PBl = sp; sp += MAT;
    short* PVh = sp; sp += MAT;   // packed B-frags of V (sigma-permuted k)
    short* PVl = sp; sp += MAT;
    float* Ep  = (float*)sp;      // nseg m-segment partials of E (last region)
    float* E2  = (float*)PAh;     // alias: PA dead after epass11

    convm<<<dim3(64, BATCH, 5), 256, 0, stream>>>(
        x, x_latter, W_low, b_low, W_val, b_val, W_mid, b_mid, W_lat, b_lat,
        W_high, b_high, XLOW, XMID, XL2, PAh, PAl, PBh, PBl, PVh, PVl);
    zpass2<<<dim3(1024), 256, 0, stream>>>(PAh, PAl, PBh, PBl, Zp);
    epass11<<<dim3(32 * nseg * 4), 512, 0, stream>>>(
        PAh, PAl, PBh, PBl, PVh, PVl, Zp, Ep, nseg);
    if (nseg == 8)
        econv6<8><<<dim3(64, BATCH), 256, 0, stream>>>(Ep, XLOW, W_ec, b_ec, E2);
    else
        econv6<4><<<dim3(64, BATCH), 256, 0, stream>>>(Ep, XLOW, W_ec, b_ec, E2);
    tmat<<<dim3(64, BATCH), 1024, 0, stream>>>(E2, XL2, T);
    softT<<<dim3(64, BATCH), 64, 0, stream>>>(T, Ts);
    outk<<<dim3(64, BATCH), 256, 0, stream>>>(XMID, Ts, outp);
}

// Round 16
// 139.561 us; speedup vs baseline: 1.6160x; 1.6160x over previous
//
#include <hip/hip_runtime.h>
#include <math.h>

// Problem constants: B=4, C=64, H=W=64 -> HW=4096
#define BATCH 4
#define CH 64
#define HW 4096
#define LOG2E 1.4426950408889634f

typedef __attribute__((ext_vector_type(8))) short short8;
typedef __attribute__((ext_vector_type(4))) float f32x4;
typedef __attribute__((ext_vector_type(4))) float float4v;
typedef __attribute__((ext_vector_type(4))) unsigned int uint4v;

#define MFMA(a, b, c) __builtin_amdgcn_mfma_f32_16x16x32_bf16(a, b, c, 0, 0, 0)

// 2^x. MUST go through the builtin (or libm), NOT raw asm: v_exp_f32 is a
// TRANS op and the compiler's hazard recognizer can't see inside an asm blob
// (R12 failed with absmax 0.84 from exactly that missing wait-state).
__device__ __forceinline__ float exp2v(float x) {
#if __has_builtin(__builtin_amdgcn_exp2f)
    return __builtin_amdgcn_exp2f(x);
#else
    return exp2f(x);
#endif
}
// pack 2 floats -> bf16 hi-word pair + exact-residual lo-word pair.
__device__ __forceinline__ void cvtpk2(float a, float b, unsigned &h, unsigned &l) {
    unsigned hv;
    asm("v_cvt_pk_bf16_f32 %0, %1, %2" : "=v"(hv) : "v"(a), "v"(b));
    float ra = a - __builtin_bit_cast(float, hv << 16);
    float rb = b - __builtin_bit_cast(float, hv & 0xffff0000u);
    unsigned lv;
    asm("v_cvt_pk_bf16_f32 %0, %1, %2" : "=v"(lv) : "v"(ra), "v"(rb));
    h = hv; l = lv;
}
// async global->LDS, 16B per lane; lds base must be wave-uniform
__device__ __forceinline__ void gld16(const short* g, short* l) {
    __builtin_amdgcn_global_load_lds(
        (const __attribute__((address_space(1))) unsigned int*)g,
        (__attribute__((address_space(3))) unsigned int*)l, 16, 0, 0);
}

// ---------------------------------------------------------------------------
// convm: 1x1 convs via 3-term split-bf16 MFMA; B-frags built inline from X
// (splitX fused away). mode: 0 W_low->XLOW fp32 + PA | 1 W_val->PV (sigma-
// permuted k) | 2 W_mid->XMID | 3 W_lat->XL2 | 4 W_high->PB (scaled by LOG2E).
// ---------------------------------------------------------------------------
__global__ __launch_bounds__(256) void convm(
    const float* __restrict__ x, const float* __restrict__ xl,
    const float* __restrict__ Wlow, const float* __restrict__ blow,
    const float* __restrict__ Wval, const float* __restrict__ bval,
    const float* __restrict__ Wmid, const float* __restrict__ bmid,
    const float* __restrict__ Wlat, const float* __restrict__ blat,
    const float* __restrict__ Whigh, const float* __restrict__ bhigh,
    float* __restrict__ XLOW, float* __restrict__ XMID, float* __restrict__ XL2,
    short* __restrict__ PAh, short* __restrict__ PAl,
    short* __restrict__ PBh, short* __restrict__ PBl,
    short* __restrict__ PVh, short* __restrict__ PVl)
{
    int mode = blockIdx.z, b = blockIdx.y, bx = blockIdx.x;
    const float* W; const float* bias; const float* X;
    switch (mode) {
        case 0:  W = Wlow;  bias = blow;  X = x;  break;
        case 1:  W = Wval;  bias = bval;  X = x;  break;
        case 2:  W = Wmid;  bias = bmid;  X = x;  break;
        case 3:  W = Wlat;  bias = blat;  X = xl; break;
        default: W = Whigh; bias = bhigh; X = xl; break;
    }
    int t = threadIdx.x, wv = t >> 6, ln = t & 63;
    int row = ln & 15, g = ln >> 4;

    // W A-frags (hi/lo)
    short8 Wh[4][2], Wlo[4][2];
    #pragma unroll
    for (int ot = 0; ot < 4; ot++)
        #pragma unroll
        for (int kt = 0; kt < 2; kt++) {
            const float* wp = W + (ot * 16 + row) * 64 + kt * 32 + g * 8;
            uint4v hw, lw;
            #pragma unroll
            for (int k2 = 0; k2 < 4; k2++) {
                unsigned h, l;
                cvtpk2(wp[2 * k2], wp[2 * k2 + 1], h, l);
                hw[k2] = h; lw[k2] = l;
            }
            Wh[ot][kt] = __builtin_bit_cast(short8, hw);
            Wlo[ot][kt] = __builtin_bit_cast(short8, lw);
        }

    // X B-frags built inline: value = X[c = kt*32+g*8+j][nt*16+row]
    int nt = bx * 4 + wv;
    short8 Bh[2], Bl[2];
    #pragma unroll
    for (int kt = 0; kt < 2; kt++) {
        float v[8];
        #pragma unroll
        for (int j = 0; j < 8; j++)
            v[j] = X[(size_t)(b * 64 + kt * 32 + g * 8 + j) * HW + nt * 16 + row];
        uint4v hw, lw;
        #pragma unroll
        for (int k2 = 0; k2 < 4; k2++) {
            unsigned h, l;
            cvtpk2(v[2 * k2], v[2 * k2 + 1], h, l);
            hw[k2] = h; lw[k2] = l;
        }
        Bh[kt] = __builtin_bit_cast(short8, hw);
        Bl[kt] = __builtin_bit_cast(short8, lw);
    }

    f32x4 acc[4];
    #pragma unroll
    for (int ot = 0; ot < 4; ot++) {
        #pragma unroll
        for (int r = 0; r < 4; r++) acc[ot][r] = bias[ot * 16 + g * 4 + r];
    }
    #pragma unroll
    for (int ot = 0; ot < 4; ot++)
        #pragma unroll
        for (int kt = 0; kt < 2; kt++) {
            acc[ot] = MFMA(Wh[ot][kt], Bh[kt], acc[ot]);
            acc[ot] = MFMA(Wh[ot][kt], Bl[kt], acc[ot]);
            acc[ot] = MFMA(Wlo[ot][kt], Bh[kt], acc[ot]);
        }

    __shared__ float Ld[64][65];
    #pragma unroll
    for (int ot = 0; ot < 4; ot++)
        #pragma unroll
        for (int r = 0; r < 4; r++)
            Ld[wv * 16 + (ln & 15)][ot * 16 + g * 4 + r] = acc[ot][r];
    __syncthreads();

    int n0 = bx * 64;
    if (mode == 0 || mode == 2 || mode == 3) {
        float* outp = (mode == 0) ? XLOW : (mode == 2) ? XMID : XL2;
        int n = t >> 2, o0 = (t & 3) * 16;
        float vout[16];
        #pragma unroll
        for (int k = 0; k < 16; k++) vout[k] = Ld[n][o0 + k];
        float* gp = outp + ((size_t)b * HW + n0 + n) * 64 + o0;
        #pragma unroll
        for (int k = 0; k < 4; k++)
            *(float4v*)(gp + k * 4) = *(float4v*)(vout + k * 4);
    }
    if (mode == 0 || mode == 4) {
        // PA (rows=n) or PB (cols=m) — same transform. PB scaled by LOG2E so
        // S' = S*log2(e) and exp(S) = 2^(S') via v_exp_f32 downstream.
        short* Ph = (mode == 0) ? PAh : PBh;
        short* Pl = (mode == 0) ? PAl : PBl;
        float scale = (mode == 4) ? LOG2E : 1.0f;
        #pragma unroll
        for (int kt = 0; kt < 2; kt++) {
            uint4v hw, lw;
            #pragma unroll
            for (int k2 = 0; k2 < 4; k2++) {
                unsigned h, l;
                cvtpk2(Ld[wv * 16 + (ln & 15)][kt * 32 + g * 8 + 2 * k2] * scale,
                       Ld[wv * 16 + (ln & 15)][kt * 32 + g * 8 + 2 * k2 + 1] * scale, h, l);
                hw[k2] = h; lw[k2] = l;
            }
            size_t blob = (((size_t)b * 256 + bx * 4 + wv) * 2 + kt) * 512 + (size_t)ln * 8;
            *(uint4v*)(Ph + blob) = hw;
            *(uint4v*)(Pl + blob) = lw;
        }
    }
    if (mode == 1) {
        // PV: B-frag, k = m with sigma-permutation: k-slot (kt, g, j) holds
        //   m_local = (kt*2 + (j>>2))*16 + g*4 + (j&3)
        int ktm_l = wv >> 1;
        int ct0 = (wv & 1) * 2;
        #pragma unroll
        for (int cc = 0; cc < 2; cc++) {
            int ct = ct0 + cc;
            int c = ct * 16 + (ln & 15);
            float v[8];
            #pragma unroll
            for (int j = 0; j < 8; j++)
                v[j] = Ld[(ktm_l * 2 + (j >> 2)) * 16 + g * 4 + (j & 3)][c];
            uint4v hw, lw;
            #pragma unroll
            for (int k2 = 0; k2 < 4; k2++) {
                unsigned h, l;
                cvtpk2(v[2 * k2], v[2 * k2 + 1], h, l);
                hw[k2] = h; lw[k2] = l;
            }
            size_t blob = (((size_t)b * 128 + bx * 2 + ktm_l) * 4 + ct) * 512 + (size_t)ln * 8;
            *(uint4v*)(PVh + blob) = hw;
            *(uint4v*)(PVl + blob) = lw;
        }
    }
}

// ---------------------------------------------------------------------------
// zpass2: Z partials; XCD swizzle; deferred cross-lane reduce; exp2 (PB is
// pre-scaled by LOG2E).
// ---------------------------------------------------------------------------
__global__ __launch_bounds__(256) void zpass2(
    const short* __restrict__ PAh, const short* __restrict__ PAl,
    const short* __restrict__ PBh, const short* __restrict__ PBl,
    float* __restrict__ Zp)
{
    int bid = blockIdx.x;
    int sw = (bid & 7) * 128 + (bid >> 3);       // XCD-bijective swizzle
    int mchunk = sw & 63, nc = (sw >> 6) & 3, b = sw >> 8;
    int t = threadIdx.x, wv = t >> 6, ln = t & 63;
    short8 bh[4][2], bl[4][2];
    #pragma unroll
    for (int msub = 0; msub < 4; msub++)
        #pragma unroll
        for (int kt = 0; kt < 2; kt++) {
            size_t o = ((size_t)(b * 256 + mchunk * 4 + msub) * 2 + kt) * 512 + ln * 8;
            bh[msub][kt] = *(const short8*)(PBh + o);
            bl[msub][kt] = *(const short8*)(PBl + o);
        }
    float zacc[4] = {0.f, 0.f, 0.f, 0.f};
    for (int s = 0; s < 16; s++) {
        int nt = nc * 64 + s * 4 + wv;
        size_t ab = ((size_t)(b * 256 + nt) * 2) * 512 + ln * 8;
        short8 ah0 = *(const short8*)(PAh + ab);
        short8 ah1 = *(const short8*)(PAh + ab + 512);
        short8 al0 = *(const short8*)(PAl + ab);
        short8 al1 = *(const short8*)(PAl + ab + 512);
        #pragma unroll
        for (int msub = 0; msub < 4; msub++) {
            f32x4 acc = {0.f, 0.f, 0.f, 0.f};
            acc = MFMA(ah0, bh[msub][0], acc);
            acc = MFMA(ah1, bh[msub][1], acc);
            acc = MFMA(ah0, bl[msub][0], acc);
            acc = MFMA(ah1, bl[msub][1], acc);
            acc = MFMA(al0, bh[msub][0], acc);
            acc = MFMA(al1, bh[msub][1], acc);
            zacc[msub] += exp2v(acc[0]) + exp2v(acc[1]) + exp2v(acc[2]) + exp2v(acc[3]);
        }
    }
    #pragma unroll
    for (int msub = 0; msub < 4; msub++) {
        zacc[msub] += __shfl_xor(zacc[msub], 16, 64);
        zacc[msub] += __shfl_xor(zacc[msub], 32, 64);
    }
    __shared__ float sZ[4][64];
    if (ln < 16) {
        #pragma unroll
        for (int msub = 0; msub < 4; msub++) sZ[wv][msub * 16 + ln] = zacc[msub];
    }
    __syncthreads();
    if (t < 64) {
        float z = sZ[0][t] + sZ[1][t] + sZ[2][t] + sZ[3][t];
        Zp[((size_t)(b * 4 + nc)) * 4096 + mchunk * 64 + t] = z;
    }
}

// ---------------------------------------------------------------------------
// epass10: KVBLK=32 core (operand-swapped S, in-register cvt_pk w) with
// exp2 via builtin (PB pre-scaled). grid (32 nb x nseg x 4 b), block 256.
// ---------------------------------------------------------------------------
__global__ __launch_bounds__(256, 3) void epass10(
    const short* __restrict__ PAh, const short* __restrict__ PAl,
    const short* __restrict__ PBh, const short* __restrict__ PBl,
    const short* __restrict__ PVh, const short* __restrict__ PVl,
    const float* __restrict__ Zp, float* __restrict__ Ep, int nseg)
{
    int nwg = 32 * nseg * 4, cpx = nwg >> 3;
    int bid = blockIdx.x;
    int sw = (bid & 7) * cpx + (bid >> 3);       // XCD-bijective
    int nb = sw & 31, mseg = (sw >> 5) % nseg, b = sw / (32 * nseg);
    int iters = 128 / nseg;                       // 32-m tiles per segment
    int mper = 4096 / nseg;
    int t = threadIdx.x, wv = t >> 6, ln = t & 63;
    int lnm = ln & 15, lnr = ln >> 4;

    __shared__ __align__(16) short sB[2][2][2048];   // 16 KB [buf][hi/lo]
    __shared__ __align__(16) short sV[2][2][2048];   // 16 KB
    __shared__ __align__(16) float sZi[1024];

    // folded zmerge
    for (int k = t; k < mper; k += 256) {
        int m = mseg * mper + k;
        float z = Zp[((size_t)(b * 4 + 0)) * 4096 + m]
                + Zp[((size_t)(b * 4 + 1)) * 4096 + m]
                + Zp[((size_t)(b * 4 + 2)) * 4096 + m]
                + Zp[((size_t)(b * 4 + 3)) * 4096 + m];
        sZi[k] = 1.f / z;
    }

    // stationary XLOW B-frags: 2 row-tiles per wave (block covers 128 n-rows)
    short8 Lh[2][2], Ll[2][2];
    #pragma unroll
    for (int rt = 0; rt < 2; rt++)
        #pragma unroll
        for (int kt = 0; kt < 2; kt++) {
            int nt = nb * 8 + wv * 2 + rt;
            size_t base = ((size_t)(b * 256 + nt) * 2 + kt) * 512 + ln * 8;
            Lh[rt][kt] = *(const short8*)(PAh + base);
            Ll[rt][kt] = *(const short8*)(PAl + base);
        }

    f32x4 acc_e[2][4];   // [rt][ct]
    #pragma unroll
    for (int rt = 0; rt < 2; rt++)
        #pragma unroll
        for (int ct = 0; ct < 4; ct++) acc_e[rt][ct] = (f32x4){0.f, 0.f, 0.f, 0.f};

    const int mt00 = mseg * (mper >> 4);
    const int ktm0 = mseg * (mper >> 5);
    #define STAGE(bufi, ii) { \
        size_t pbb = (size_t)b * 262144 + (size_t)(mt00 + (ii) * 2) * 1024; \
        size_t pvb = (size_t)b * 262144 + (size_t)(ktm0 + (ii)) * 2048; \
        gld16(PBh + pbb + t * 8, &sB[bufi][0][wv * 512]); \
        gld16(PBl + pbb + t * 8, &sB[bufi][1][wv * 512]); \
        gld16(PVh + pvb + t * 8, &sV[bufi][0][wv * 512]); \
        gld16(PVl + pvb + t * 8, &sV[bufi][1][wv * 512]); }

    STAGE(0, 0);
    __syncthreads();

    for (int i = 0; i < iters; i++) {
        int cur = i & 1;
        if (i + 1 < iters) STAGE(cur ^ 1, i + 1);

        // ---- S'^T (3-term, swapped operands); w = 2^(S') * Zi
        f32x4 wf[2][2];   // [rt][ms]
        #pragma unroll
        for (int ms = 0; ms < 2; ms++) {
            const short8 bh0 = *(const short8*)&sB[cur][0][(ms * 2 + 0) * 512 + ln * 8];
            const short8 bh1 = *(const short8*)&sB[cur][0][(ms * 2 + 1) * 512 + ln * 8];
            const short8 bl0 = *(const short8*)&sB[cur][1][(ms * 2 + 0) * 512 + ln * 8];
            const short8 bl1 = *(const short8*)&sB[cur][1][(ms * 2 + 1) * 512 + ln * 8];
            const f32x4 vz = *(const f32x4*)&sZi[i * 32 + ms * 16 + lnr * 4];
            __builtin_amdgcn_s_setprio(1);
            #pragma unroll
            for (int rt = 0; rt < 2; rt++) {
                f32x4 acc = {0.f, 0.f, 0.f, 0.f};
                acc = MFMA(bh0, Lh[rt][0], acc);
                acc = MFMA(bh1, Lh[rt][1], acc);
                acc = MFMA(bh0, Ll[rt][0], acc);
                acc = MFMA(bh1, Ll[rt][1], acc);
                acc = MFMA(bl0, Lh[rt][0], acc);
                acc = MFMA(bl1, Lh[rt][1], acc);
                #pragma unroll
                for (int r = 0; r < 4; r++)
                    wf[rt][ms][r] = exp2v(acc[r]) * vz[r];
            }
            __builtin_amdgcn_s_setprio(0);
        }
        // ---- pack P A-frags via cvt_pk (sigma: j-slot <- wf[j>>2][j&3])
        short8 pah[2], pal[2];
        #pragma unroll
        for (int rt = 0; rt < 2; rt++) {
            uint4v hw, lw;
            #pragma unroll
            for (int k2 = 0; k2 < 4; k2++) {
                unsigned h, l;
                cvtpk2(wf[rt][k2 >> 1][2 * (k2 & 1)],
                       wf[rt][k2 >> 1][2 * (k2 & 1) + 1], h, l);
                hw[k2] = h; lw[k2] = l;
            }
            pah[rt] = __builtin_bit_cast(short8, hw);
            pal[rt] = __builtin_bit_cast(short8, lw);
        }
        // ---- PV (K=32): acc_e += pah*(vh+vl) + pal*vh
        __builtin_amdgcn_s_setprio(1);
        #pragma unroll
        for (int ct = 0; ct < 4; ct++) {
            const short8 vh = *(const short8*)&sV[cur][0][ct * 512 + ln * 8];
            const short8 vl = *(const short8*)&sV[cur][1][ct * 512 + ln * 8];
            #pragma unroll
            for (int rt = 0; rt < 2; rt++) {
                acc_e[rt][ct] = MFMA(pah[rt], vh, acc_e[rt][ct]);
                acc_e[rt][ct] = MFMA(pah[rt], vl, acc_e[rt][ct]);
                acc_e[rt][ct] = MFMA(pal[rt], vh, acc_e[rt][ct]);
            }
        }
        __builtin_amdgcn_s_setprio(0);
        __syncthreads();
    }
    #undef STAGE

    // epilogue: fp32 partials Ep[mseg][b][n][c]
    float* ep = Ep + ((size_t)mseg * BATCH + b) * HW * 64;
    #pragma unroll
    for (int rt = 0; rt < 2; rt++) {
        int n0 = (nb * 8 + wv * 2 + rt) * 16 + lnr * 4;
        #pragma unroll
        for (int ct = 0; ct < 4; ct++) {
            #pragma unroll
            for (int r = 0; r < 4; r++)
                ep[(size_t)(n0 + r) * 64 + ct * 16 + lnm] = acc_e[rt][ct][r];
        }
    }
}

// ---------------------------------------------------------------------------
// econv6<NSEG>: E1 = sum(NSEG partials) + XLOW, then E2 = W_ec*E1 + b_ec.
// Fully unrolled float4 partial-sum.
// ---------------------------------------------------------------------------
template <int NSEG>
__global__ __launch_bounds__(256) void econv6(
    const float* __restrict__ Ep, const float* __restrict__ XLOW,
    const float* __restrict__ W, const float* __restrict__ bias,
    float* __restrict__ E2)
{
    const size_t SEG = (size_t)BATCH * HW * 64;
    int b = blockIdx.y, n0 = blockIdx.x * 64, t = threadIdx.x;
    __shared__ float Wl[64][64];
    __shared__ float El[64][65];
    for (int i = t; i < 4096; i += 256) Wl[i >> 6][i & 63] = W[i];
    for (int q = t; q < 1024; q += 256) {          // q indexes float4 groups
        int nl = q >> 4, c0 = (q & 15) * 4;
        size_t idx = ((size_t)b * HW + n0 + nl) * 64 + c0;
        float4v s = *(const float4v*)(XLOW + idx);
        #pragma unroll
        for (int sg = 0; sg < NSEG; sg++) {
            float4v p = *(const float4v*)(Ep + sg * SEG + idx);
            s.x += p.x; s.y += p.y; s.z += p.z; s.w += p.w;
        }
        El[nl][c0] = s.x; El[nl][c0 + 1] = s.y;
        El[nl][c0 + 2] = s.z; El[nl][c0 + 3] = s.w;
    }
    __syncthreads();
    int nl = t & 63, og = t >> 6;
    for (int k = 0; k < 16; k++) {
        int o = og * 16 + k;
        float a0 = bias[o], a1 = 0.f, a2 = 0.f, a3 = 0.f;
        #pragma unroll
        for (int c = 0; c < 64; c += 4) {
            a0 += Wl[o][c]     * El[nl][c];
            a1 += Wl[o][c + 1] * El[nl][c + 1];
            a2 += Wl[o][c + 2] * El[nl][c + 2];
            a3 += Wl[o][c + 3] * El[nl][c + 3];
        }
        E2[((size_t)b * 64 + o) * HW + n0 + nl] = (a0 + a1) + (a2 + a3);
    }
}

// ---------------------------------------------------------------------------
// tmat: T[b][c][d] = sum_n E2[b][c][n] * XL2[b][n][d]; block 1024
// ---------------------------------------------------------------------------
__global__ __launch_bounds__(1024) void tmat(
    const float* __restrict__ E2, const float* __restrict__ XL2, float* __restrict__ T)
{
    int b = blockIdx.y, c = blockIdx.x, t = threadIdx.x;
    int d = t & 63, nl = t >> 6;   // nl 0..15
    const float* e = E2 + ((size_t)b * 64 + c) * HW;
    const float* x2 = XL2 + (size_t)b * HW * 64;
    float a0 = 0.f, a1 = 0.f;
    #pragma unroll 4
    for (int k = 0; k < 256; k += 2) {
        int na = k * 16 + nl, nb2 = na + 16;
        a0 += e[na] * x2[(size_t)na * 64 + d];
        a1 += e[nb2] * x2[(size_t)nb2 * 64 + d];
    }
    __shared__ float red[16][64];
    red[nl][d] = a0 + a1;
    __syncthreads();
    if (t < 64) {
        float s = 0.f;
        #pragma unroll
        for (int j = 0; j < 16; j++) s += red[j][t];
        T[((size_t)b * 64 + c) * 64 + t] = s;
    }
}

// softmax over c for each (b, d)
__global__ __launch_bounds__(64) void softT(
    const float* __restrict__ T, float* __restrict__ Ts)
{
    int d = blockIdx.x, b = blockIdx.y, c = threadIdx.x;
    float v = T[((size_t)b * 64 + c) * 64 + d];
    float M = v;
    #pragma unroll
    for (int o = 32; o > 0; o >>= 1) M = fmaxf(M, __shfl_xor(M, o, 64));
    float ez = __expf(v - M);
    float Z = ez;
    #pragma unroll
    for (int o = 32; o > 0; o >>= 1) Z += __shfl_xor(Z, o, 64);
    Ts[((size_t)b * 64 + c) * 64 + d] = ez / Z;
}

// out[b][d][n] = sum_c XMID[b][n][c] * Ts[b][c][d]
__global__ __launch_bounds__(256) void outk(
    const float* __restrict__ XMID, const float* __restrict__ Ts, float* __restrict__ out)
{
    int b = blockIdx.y, n0 = blockIdx.x * 64, t = threadIdx.x;
    __shared__ float Xm[64][65];
    __shared__ float Tl[64][64];
    for (int i = t; i < 4096; i += 256) {
        int nl = i >> 6, c = i & 63;
        Xm[nl][c] = XMID[((size_t)b * HW + n0 + nl) * 64 + c];
    }
    for (int i = t; i < 4096; i += 256) Tl[i >> 6][i & 63] = Ts[(size_t)b * 4096 + i];
    __syncthreads();
    int nl = t & 63, dg = t >> 6;
    float accs[16];
    #pragma unroll
    for (int k = 0; k < 16; k++) accs[k] = 0.f;
    for (int c = 0; c < 64; c++) {
        float xv = Xm[nl][c];
        #pragma unroll
        for (int k = 0; k < 16; k++) accs[k] += xv * Tl[c][dg * 16 + k];
    }
    #pragma unroll
    for (int k = 0; k < 16; k++) {
        int d = dg * 16 + k;
        out[((size_t)b * 64 + d) * HW + n0 + nl] = accs[k];
    }
}

// ---------------------------------------------------------------------------
extern "C" void kernel_launch(void* const* d_in, const int* in_sizes, int n_in,
                              void* d_out, int out_size, void* d_ws, size_t ws_size,
                              hipStream_t stream)
{
    const float* x_latter = (const float*)d_in[0];
    const float* x        = (const float*)d_in[1];
    const float* W_high = (const float*)d_in[2];  const float* b_high = (const float*)d_in[3];
    const float* W_low  = (const float*)d_in[4];  const float* b_low  = (const float*)d_in[5];
    const float* W_val  = (const float*)d_in[6];  const float* b_val  = (const float*)d_in[7];
    const float* W_ec   = (const float*)d_in[8];  const float* b_ec   = (const float*)d_in[9];
    const float* W_mid  = (const float*)d_in[10]; const float* b_mid  = (const float*)d_in[11];
    const float* W_lat  = (const float*)d_in[12]; const float* b_lat  = (const float*)d_in[13];
    float* outp = (float*)d_out;

    const size_t MAT = (size_t)BATCH * CH * HW;  // 1,048,576 elements

    // ws budget: fixed floats (3 MAT + Zp + T + Ts) + 6 MAT shorts + Ep(nseg MAT)
    const size_t fixed_f = 3 * MAT + (size_t)BATCH * 4 * HW + 2 * (size_t)BATCH * 64 * 64;
    const size_t need8 = (fixed_f + 8 * MAT) * 4 + 6 * MAT * 2;
    int nseg = (ws_size >= need8) ? 8 : 4;

    float* ws = (float*)d_ws;
    size_t off = 0;
    float* XLOW = ws + off; off += MAT;              // [b][n][c]
    float* XMID = ws + off; off += MAT;              // [b][n][c]
    float* XL2  = ws + off; off += MAT;              // [b][n][d]
    float* Zp   = ws + off; off += (size_t)BATCH * 4 * HW;
    float* T    = ws + off; off += (size_t)BATCH * 64 * 64;
    float* Ts   = ws + off; off += (size_t)BATCH * 64 * 64;
    short* sp = (short*)(ws + off);
    short* PAh = sp; sp += MAT;   // packed frags of XLOW (hi)
    short* PAl = sp; sp += MAT;
    short* PBh = sp; sp += MAT;   // packed frags of XLHI (pre-scaled by LOG2E)
    short* PBl = sp; sp += MAT;
    short* PVh = sp; sp += MAT;   // packed B-frags of V (sigma-permuted k)
    short* PVl = sp; sp += MAT;
    float* Ep  = (float*)sp;      // nseg m-segment partials of E (last region)
    float* E2  = (float*)PAh;     // alias: PA dead after epass10

    convm<<<dim3(64, BATCH, 5), 256, 0, stream>>>(
        x, x_latter, W_low, b_low, W_val, b_val, W_mid, b_mid, W_lat, b_lat,
        W_high, b_high, XLOW, XMID, XL2, PAh, PAl, PBh, PBl, PVh, PVl);
    zpass2<<<dim3(1024), 256, 0, stream>>>(PAh, PAl, PBh, PBl, Zp);
    epass10<<<dim3(32 * nseg * 4), 256, 0, stream>>>(
        PAh, PAl, PBh, PBl, PVh, PVl, Zp, Ep, nseg);
    if (nseg == 8)
        econv6<8><<<dim3(64, BATCH), 256, 0, stream>>>(Ep, XLOW, W_ec, b_ec, E2);
    else
        econv6<4><<<dim3(64, BATCH), 256, 0, stream>>>(Ep, XLOW, W_ec, b_ec, E2);
    tmat<<<dim3(64, BATCH), 1024, 0, stream>>>(E2, XL2, T);
    softT<<<dim3(64, BATCH), 64, 0, stream>>>(T, Ts);
    outk<<<dim3(64, BATCH), 256, 0, stream>>>(XMID, Ts, outp);
}

// Round 17
// 138.722 us; speedup vs baseline: 1.6258x; 1.0060x over previous
//
#include <hip/hip_runtime.h>
#include <math.h>

// Problem constants: B=4, C=64, H=W=64 -> HW=4096
#define BATCH 4
#define CH 64
#define HW 4096
#define LOG2E 1.4426950408889634f

typedef __attribute__((ext_vector_type(8))) short short8;
typedef __attribute__((ext_vector_type(4))) float f32x4;
typedef __attribute__((ext_vector_type(4))) float float4v;
typedef __attribute__((ext_vector_type(4))) unsigned int uint4v;

#define MFMA(a, b, c) __builtin_amdgcn_mfma_f32_16x16x32_bf16(a, b, c, 0, 0, 0)

// 2^x. MUST go through the builtin (or libm), NOT raw asm: v_exp_f32 is a
// TRANS op and the compiler's hazard recognizer can't see inside an asm blob
// (R12 failed with absmax 0.84 from exactly that missing wait-state).
__device__ __forceinline__ float exp2v(float x) {
#if __has_builtin(__builtin_amdgcn_exp2f)
    return __builtin_amdgcn_exp2f(x);
#else
    return exp2f(x);
#endif
}
// pack 2 floats -> bf16 hi-word pair + exact-residual lo-word pair.
__device__ __forceinline__ void cvtpk2(float a, float b, unsigned &h, unsigned &l) {
    unsigned hv;
    asm("v_cvt_pk_bf16_f32 %0, %1, %2" : "=v"(hv) : "v"(a), "v"(b));
    float ra = a - __builtin_bit_cast(float, hv << 16);
    float rb = b - __builtin_bit_cast(float, hv & 0xffff0000u);
    unsigned lv;
    asm("v_cvt_pk_bf16_f32 %0, %1, %2" : "=v"(lv) : "v"(ra), "v"(rb));
    h = hv; l = lv;
}
// async global->LDS, 16B per lane; lds base must be wave-uniform
__device__ __forceinline__ void gld16(const short* g, short* l) {
    __builtin_amdgcn_global_load_lds(
        (const __attribute__((address_space(1))) unsigned int*)g,
        (__attribute__((address_space(3))) unsigned int*)l, 16, 0, 0);
}

// ---------------------------------------------------------------------------
// wpack: pre-pack the 5 weight matrices into MFMA A-frag hi/lo blobs, once.
// Blob (mode, ot, kt): [ln*8 + j] = W[(ot*16 + (ln&15))*64 + kt*32 + (ln>>4)*8 + j]
// grid (5), 256 thr (thread = (ot, ln)). (Proven correct in R14.)
// ---------------------------------------------------------------------------
__global__ __launch_bounds__(256) void wpack(
    const float* __restrict__ Wlow, const float* __restrict__ Wval,
    const float* __restrict__ Wmid, const float* __restrict__ Wlat,
    const float* __restrict__ Whigh,
    short* __restrict__ WFh, short* __restrict__ WFl)
{
    int mode = blockIdx.x;
    const float* W;
    switch (mode) {
        case 0: W = Wlow; break;  case 1: W = Wval; break;
        case 2: W = Wmid; break;  case 3: W = Wlat; break;
        default: W = Whigh; break;
    }
    int t = threadIdx.x, ot = t >> 6, ln = t & 63;
    int row = ln & 15, g = ln >> 4;
    #pragma unroll
    for (int kt = 0; kt < 2; kt++) {
        const float* wp = W + (ot * 16 + row) * 64 + kt * 32 + g * 8;
        uint4v hw, lw;
        #pragma unroll
        for (int k2 = 0; k2 < 4; k2++) {
            unsigned h, l;
            cvtpk2(wp[2 * k2], wp[2 * k2 + 1], h, l);
            hw[k2] = h; lw[k2] = l;
        }
        size_t blob = ((size_t)(mode * 8 + ot * 2 + kt)) * 512 + (size_t)ln * 8;
        *(uint4v*)(WFh + blob) = hw;
        *(uint4v*)(WFl + blob) = lw;
    }
}

// ---------------------------------------------------------------------------
// convm: 1x1 convs via 3-term split-bf16 MFMA; W-frags pre-packed (wpack),
// X B-frags built inline. mode: 0 W_low->XLOW fp32 + PA | 1 W_val->PV (sigma-
// permuted k) | 2 W_mid->XMID | 3 W_lat->XL2 | 4 W_high->PB (scaled by LOG2E).
// (R14-proven convm body; R13-proven everything downstream.)
// ---------------------------------------------------------------------------
__global__ __launch_bounds__(256) void convm(
    const float* __restrict__ x, const float* __restrict__ xl,
    const short* __restrict__ WFh, const short* __restrict__ WFl,
    const float* __restrict__ blow, const float* __restrict__ bval,
    const float* __restrict__ bmid, const float* __restrict__ blat,
    const float* __restrict__ bhigh,
    float* __restrict__ XLOW, float* __restrict__ XMID, float* __restrict__ XL2,
    short* __restrict__ PAh, short* __restrict__ PAl,
    short* __restrict__ PBh, short* __restrict__ PBl,
    short* __restrict__ PVh, short* __restrict__ PVl)
{
    int mode = blockIdx.z, b = blockIdx.y, bx = blockIdx.x;
    const float* bias; const float* X;
    switch (mode) {
        case 0:  bias = blow;  X = x;  break;
        case 1:  bias = bval;  X = x;  break;
        case 2:  bias = bmid;  X = x;  break;
        case 3:  bias = blat;  X = xl; break;
        default: bias = bhigh; X = xl; break;
    }
    int t = threadIdx.x, wv = t >> 6, ln = t & 63;
    int row = ln & 15, g = ln >> 4;

    // W A-frags: pre-packed by wpack (16 x b128 loads, no VALU)
    short8 Wh[4][2], Wlo[4][2];
    #pragma unroll
    for (int ot = 0; ot < 4; ot++)
        #pragma unroll
        for (int kt = 0; kt < 2; kt++) {
            size_t blob = ((size_t)(mode * 8 + ot * 2 + kt)) * 512 + (size_t)ln * 8;
            Wh[ot][kt] = *(const short8*)(WFh + blob);
            Wlo[ot][kt] = *(const short8*)(WFl + blob);
        }

    // X B-frags built inline: value = X[c = kt*32+g*8+j][nt*16+row]
    int nt = bx * 4 + wv;
    short8 Bh[2], Bl[2];
    #pragma unroll
    for (int kt = 0; kt < 2; kt++) {
        float v[8];
        #pragma unroll
        for (int j = 0; j < 8; j++)
            v[j] = X[(size_t)(b * 64 + kt * 32 + g * 8 + j) * HW + nt * 16 + row];
        uint4v hw, lw;
        #pragma unroll
        for (int k2 = 0; k2 < 4; k2++) {
            unsigned h, l;
            cvtpk2(v[2 * k2], v[2 * k2 + 1], h, l);
            hw[k2] = h; lw[k2] = l;
        }
        Bh[kt] = __builtin_bit_cast(short8, hw);
        Bl[kt] = __builtin_bit_cast(short8, lw);
    }

    f32x4 acc[4];
    #pragma unroll
    for (int ot = 0; ot < 4; ot++) {
        #pragma unroll
        for (int r = 0; r < 4; r++) acc[ot][r] = bias[ot * 16 + g * 4 + r];
    }
    #pragma unroll
    for (int ot = 0; ot < 4; ot++)
        #pragma unroll
        for (int kt = 0; kt < 2; kt++) {
            acc[ot] = MFMA(Wh[ot][kt], Bh[kt], acc[ot]);
            acc[ot] = MFMA(Wh[ot][kt], Bl[kt], acc[ot]);
            acc[ot] = MFMA(Wlo[ot][kt], Bh[kt], acc[ot]);
        }

    __shared__ float Ld[64][65];
    #pragma unroll
    for (int ot = 0; ot < 4; ot++)
        #pragma unroll
        for (int r = 0; r < 4; r++)
            Ld[wv * 16 + (ln & 15)][ot * 16 + g * 4 + r] = acc[ot][r];
    __syncthreads();

    int n0 = bx * 64;
    if (mode == 0 || mode == 2 || mode == 3) {
        float* outp = (mode == 0) ? XLOW : (mode == 2) ? XMID : XL2;
        int n = t >> 2, o0 = (t & 3) * 16;
        float vout[16];
        #pragma unroll
        for (int k = 0; k < 16; k++) vout[k] = Ld[n][o0 + k];
        float* gp = outp + ((size_t)b * HW + n0 + n) * 64 + o0;
        #pragma unroll
        for (int k = 0; k < 4; k++)
            *(float4v*)(gp + k * 4) = *(float4v*)(vout + k * 4);
    }
    if (mode == 0 || mode == 4) {
        // PA (rows=n) or PB (cols=m) — same transform. PB scaled by LOG2E so
        // S' = S*log2(e) and exp(S) = 2^(S') via v_exp_f32 downstream.
        short* Ph = (mode == 0) ? PAh : PBh;
        short* Pl = (mode == 0) ? PAl : PBl;
        float scale = (mode == 4) ? LOG2E : 1.0f;
        #pragma unroll
        for (int kt = 0; kt < 2; kt++) {
            uint4v hw, lw;
            #pragma unroll
            for (int k2 = 0; k2 < 4; k2++) {
                unsigned h, l;
                cvtpk2(Ld[wv * 16 + (ln & 15)][kt * 32 + g * 8 + 2 * k2] * scale,
                       Ld[wv * 16 + (ln & 15)][kt * 32 + g * 8 + 2 * k2 + 1] * scale, h, l);
                hw[k2] = h; lw[k2] = l;
            }
            size_t blob = (((size_t)b * 256 + bx * 4 + wv) * 2 + kt) * 512 + (size_t)ln * 8;
            *(uint4v*)(Ph + blob) = hw;
            *(uint4v*)(Pl + blob) = lw;
        }
    }
    if (mode == 1) {
        // PV: B-frag, k = m with sigma-permutation: k-slot (kt, g, j) holds
        //   m_local = (kt*2 + (j>>2))*16 + g*4 + (j&3)
        int ktm_l = wv >> 1;
        int ct0 = (wv & 1) * 2;
        #pragma unroll
        for (int cc = 0; cc < 2; cc++) {
            int ct = ct0 + cc;
            int c = ct * 16 + (ln & 15);
            float v[8];
            #pragma unroll
            for (int j = 0; j < 8; j++)
                v[j] = Ld[(ktm_l * 2 + (j >> 2)) * 16 + g * 4 + (j & 3)][c];
            uint4v hw, lw;
            #pragma unroll
            for (int k2 = 0; k2 < 4; k2++) {
                unsigned h, l;
                cvtpk2(v[2 * k2], v[2 * k2 + 1], h, l);
                hw[k2] = h; lw[k2] = l;
            }
            size_t blob = (((size_t)b * 128 + bx * 2 + ktm_l) * 4 + ct) * 512 + (size_t)ln * 8;
            *(uint4v*)(PVh + blob) = hw;
            *(uint4v*)(PVl + blob) = lw;
        }
    }
}

// ---------------------------------------------------------------------------
// zpass2: Z partials; XCD swizzle; deferred cross-lane reduce; exp2 (PB is
// pre-scaled by LOG2E). (R13-proven.)
// ---------------------------------------------------------------------------
__global__ __launch_bounds__(256) void zpass2(
    const short* __restrict__ PAh, const short* __restrict__ PAl,
    const short* __restrict__ PBh, const short* __restrict__ PBl,
    float* __restrict__ Zp)
{
    int bid = blockIdx.x;
    int sw = (bid & 7) * 128 + (bid >> 3);       // XCD-bijective swizzle
    int mchunk = sw & 63, nc = (sw >> 6) & 3, b = sw >> 8;
    int t = threadIdx.x, wv = t >> 6, ln = t & 63;
    short8 bh[4][2], bl[4][2];
    #pragma unroll
    for (int msub = 0; msub < 4; msub++)
        #pragma unroll
        for (int kt = 0; kt < 2; kt++) {
            size_t o = ((size_t)(b * 256 + mchunk * 4 + msub) * 2 + kt) * 512 + ln * 8;
            bh[msub][kt] = *(const short8*)(PBh + o);
            bl[msub][kt] = *(const short8*)(PBl + o);
        }
    float zacc[4] = {0.f, 0.f, 0.f, 0.f};
    for (int s = 0; s < 16; s++) {
        int nt = nc * 64 + s * 4 + wv;
        size_t ab = ((size_t)(b * 256 + nt) * 2) * 512 + ln * 8;
        short8 ah0 = *(const short8*)(PAh + ab);
        short8 ah1 = *(const short8*)(PAh + ab + 512);
        short8 al0 = *(const short8*)(PAl + ab);
        short8 al1 = *(const short8*)(PAl + ab + 512);
        #pragma unroll
        for (int msub = 0; msub < 4; msub++) {
            f32x4 acc = {0.f, 0.f, 0.f, 0.f};
            acc = MFMA(ah0, bh[msub][0], acc);
            acc = MFMA(ah1, bh[msub][1], acc);
            acc = MFMA(ah0, bl[msub][0], acc);
            acc = MFMA(ah1, bl[msub][1], acc);
            acc = MFMA(al0, bh[msub][0], acc);
            acc = MFMA(al1, bh[msub][1], acc);
            zacc[msub] += exp2v(acc[0]) + exp2v(acc[1]) + exp2v(acc[2]) + exp2v(acc[3]);
        }
    }
    #pragma unroll
    for (int msub = 0; msub < 4; msub++) {
        zacc[msub] += __shfl_xor(zacc[msub], 16, 64);
        zacc[msub] += __shfl_xor(zacc[msub], 32, 64);
    }
    __shared__ float sZ[4][64];
    if (ln < 16) {
        #pragma unroll
        for (int msub = 0; msub < 4; msub++) sZ[wv][msub * 16 + ln] = zacc[msub];
    }
    __syncthreads();
    if (t < 64) {
        float z = sZ[0][t] + sZ[1][t] + sZ[2][t] + sZ[3][t];
        Zp[((size_t)(b * 4 + nc)) * 4096 + mchunk * 64 + t] = z;
    }
}

// ---------------------------------------------------------------------------
// epass10: KVBLK=32 core (operand-swapped S, in-register cvt_pk w) with
// exp2 via builtin (PB pre-scaled). grid (32 nb x nseg x 4 b), block 256.
// (R13-proven.)
// ---------------------------------------------------------------------------
__global__ __launch_bounds__(256, 3) void epass10(
    const short* __restrict__ PAh, const short* __restrict__ PAl,
    const short* __restrict__ PBh, const short* __restrict__ PBl,
    const short* __restrict__ PVh, const short* __restrict__ PVl,
    const float* __restrict__ Zp, float* __restrict__ Ep, int nseg)
{
    int nwg = 32 * nseg * 4, cpx = nwg >> 3;
    int bid = blockIdx.x;
    int sw = (bid & 7) * cpx + (bid >> 3);       // XCD-bijective
    int nb = sw & 31, mseg = (sw >> 5) % nseg, b = sw / (32 * nseg);
    int iters = 128 / nseg;                       // 32-m tiles per segment
    int mper = 4096 / nseg;
    int t = threadIdx.x, wv = t >> 6, ln = t & 63;
    int lnm = ln & 15, lnr = ln >> 4;

    __shared__ __align__(16) short sB[2][2][2048];   // 16 KB [buf][hi/lo]
    __shared__ __align__(16) short sV[2][2][2048];   // 16 KB
    __shared__ __align__(16) float sZi[1024];

    // folded zmerge
    for (int k = t; k < mper; k += 256) {
        int m = mseg * mper + k;
        float z = Zp[((size_t)(b * 4 + 0)) * 4096 + m]
                + Zp[((size_t)(b * 4 + 1)) * 4096 + m]
                + Zp[((size_t)(b * 4 + 2)) * 4096 + m]
                + Zp[((size_t)(b * 4 + 3)) * 4096 + m];
        sZi[k] = 1.f / z;
    }

    // stationary XLOW B-frags: 2 row-tiles per wave (block covers 128 n-rows)
    short8 Lh[2][2], Ll[2][2];
    #pragma unroll
    for (int rt = 0; rt < 2; rt++)
        #pragma unroll
        for (int kt = 0; kt < 2; kt++) {
            int nt = nb * 8 + wv * 2 + rt;
            size_t base = ((size_t)(b * 256 + nt) * 2 + kt) * 512 + ln * 8;
            Lh[rt][kt] = *(const short8*)(PAh + base);
            Ll[rt][kt] = *(const short8*)(PAl + base);
        }

    f32x4 acc_e[2][4];   // [rt][ct]
    #pragma unroll
    for (int rt = 0; rt < 2; rt++)
        #pragma unroll
        for (int ct = 0; ct < 4; ct++) acc_e[rt][ct] = (f32x4){0.f, 0.f, 0.f, 0.f};

    const int mt00 = mseg * (mper >> 4);
    const int ktm0 = mseg * (mper >> 5);
    #define STAGE(bufi, ii) { \
        size_t pbb = (size_t)b * 262144 + (size_t)(mt00 + (ii) * 2) * 1024; \
        size_t pvb = (size_t)b * 262144 + (size_t)(ktm0 + (ii)) * 2048; \
        gld16(PBh + pbb + t * 8, &sB[bufi][0][wv * 512]); \
        gld16(PBl + pbb + t * 8, &sB[bufi][1][wv * 512]); \
        gld16(PVh + pvb + t * 8, &sV[bufi][0][wv * 512]); \
        gld16(PVl + pvb + t * 8, &sV[bufi][1][wv * 512]); }

    STAGE(0, 0);
    __syncthreads();

    for (int i = 0; i < iters; i++) {
        int cur = i & 1;
        if (i + 1 < iters) STAGE(cur ^ 1, i + 1);

        // ---- S'^T (3-term, swapped operands); w = 2^(S') * Zi
        f32x4 wf[2][2];   // [rt][ms]
        #pragma unroll
        for (int ms = 0; ms < 2; ms++) {
            const short8 bh0 = *(const short8*)&sB[cur][0][(ms * 2 + 0) * 512 + ln * 8];
            const short8 bh1 = *(const short8*)&sB[cur][0][(ms * 2 + 1) * 512 + ln * 8];
            const short8 bl0 = *(const short8*)&sB[cur][1][(ms * 2 + 0) * 512 + ln * 8];
            const short8 bl1 = *(const short8*)&sB[cur][1][(ms * 2 + 1) * 512 + ln * 8];
            const f32x4 vz = *(const f32x4*)&sZi[i * 32 + ms * 16 + lnr * 4];
            __builtin_amdgcn_s_setprio(1);
            #pragma unroll
            for (int rt = 0; rt < 2; rt++) {
                f32x4 acc = {0.f, 0.f, 0.f, 0.f};
                acc = MFMA(bh0, Lh[rt][0], acc);
                acc = MFMA(bh1, Lh[rt][1], acc);
                acc = MFMA(bh0, Ll[rt][0], acc);
                acc = MFMA(bh1, Ll[rt][1], acc);
                acc = MFMA(bl0, Lh[rt][0], acc);
                acc = MFMA(bl1, Lh[rt][1], acc);
                #pragma unroll
                for (int r = 0; r < 4; r++)
                    wf[rt][ms][r] = exp2v(acc[r]) * vz[r];
            }
            __builtin_amdgcn_s_setprio(0);
        }
        // ---- pack P A-frags via cvt_pk (sigma: j-slot <- wf[j>>2][j&3])
        short8 pah[2], pal[2];
        #pragma unroll
        for (int rt = 0; rt < 2; rt++) {
            uint4v hw, lw;
            #pragma unroll
            for (int k2 = 0; k2 < 4; k2++) {
                unsigned h, l;
                cvtpk2(wf[rt][k2 >> 1][2 * (k2 & 1)],
                       wf[rt][k2 >> 1][2 * (k2 & 1) + 1], h, l);
                hw[k2] = h; lw[k2] = l;
            }
            pah[rt] = __builtin_bit_cast(short8, hw);
            pal[rt] = __builtin_bit_cast(short8, lw);
        }
        // ---- PV (K=32): acc_e += pah*(vh+vl) + pal*vh
        __builtin_amdgcn_s_setprio(1);
        #pragma unroll
        for (int ct = 0; ct < 4; ct++) {
            const short8 vh = *(const short8*)&sV[cur][0][ct * 512 + ln * 8];
            const short8 vl = *(const short8*)&sV[cur][1][ct * 512 + ln * 8];
            #pragma unroll
            for (int rt = 0; rt < 2; rt++) {
                acc_e[rt][ct] = MFMA(pah[rt], vh, acc_e[rt][ct]);
                acc_e[rt][ct] = MFMA(pah[rt], vl, acc_e[rt][ct]);
                acc_e[rt][ct] = MFMA(pal[rt], vh, acc_e[rt][ct]);
            }
        }
        __builtin_amdgcn_s_setprio(0);
        __syncthreads();
    }
    #undef STAGE

    // epilogue: fp32 partials Ep[mseg][b][n][c]
    float* ep = Ep + ((size_t)mseg * BATCH + b) * HW * 64;
    #pragma unroll
    for (int rt = 0; rt < 2; rt++) {
        int n0 = (nb * 8 + wv * 2 + rt) * 16 + lnr * 4;
        #pragma unroll
        for (int ct = 0; ct < 4; ct++) {
            #pragma unroll
            for (int r = 0; r < 4; r++)
                ep[(size_t)(n0 + r) * 64 + ct * 16 + lnm] = acc_e[rt][ct][r];
        }
    }
}

// ---------------------------------------------------------------------------
// econv6<NSEG>: E1 = sum(NSEG partials) + XLOW, then E2 = W_ec*E1 + b_ec.
// ---------------------------------------------------------------------------
template <int NSEG>
__global__ __launch_bounds__(256) void econv6(
    const float* __restrict__ Ep, const float* __restrict__ XLOW,
    const float* __restrict__ W, const float* __restrict__ bias,
    float* __restrict__ E2)
{
    const size_t SEG = (size_t)BATCH * HW * 64;
    int b = blockIdx.y, n0 = blockIdx.x * 64, t = threadIdx.x;
    __shared__ float Wl[64][64];
    __shared__ float El[64][65];
    for (int i = t; i < 4096; i += 256) Wl[i >> 6][i & 63] = W[i];
    for (int q = t; q < 1024; q += 256) {          // q indexes float4 groups
        int nl = q >> 4, c0 = (q & 15) * 4;
        size_t idx = ((size_t)b * HW + n0 + nl) * 64 + c0;
        float4v s = *(const float4v*)(XLOW + idx);
        #pragma unroll
        for (int sg = 0; sg < NSEG; sg++) {
            float4v p = *(const float4v*)(Ep + sg * SEG + idx);
            s.x += p.x; s.y += p.y; s.z += p.z; s.w += p.w;
        }
        El[nl][c0] = s.x; El[nl][c0 + 1] = s.y;
        El[nl][c0 + 2] = s.z; El[nl][c0 + 3] = s.w;
    }
    __syncthreads();
    int nl = t & 63, og = t >> 6;
    for (int k = 0; k < 16; k++) {
        int o = og * 16 + k;
        float a0 = bias[o], a1 = 0.f, a2 = 0.f, a3 = 0.f;
        #pragma unroll
        for (int c = 0; c < 64; c += 4) {
            a0 += Wl[o][c]     * El[nl][c];
            a1 += Wl[o][c + 1] * El[nl][c + 1];
            a2 += Wl[o][c + 2] * El[nl][c + 2];
            a3 += Wl[o][c + 3] * El[nl][c + 3];
        }
        E2[((size_t)b * 64 + o) * HW + n0 + nl] = (a0 + a1) + (a2 + a3);
    }
}

// ---------------------------------------------------------------------------
// tmat: T[b][c][d] = sum_n E2[b][c][n] * XL2[b][n][d]; block 1024
// ---------------------------------------------------------------------------
__global__ __launch_bounds__(1024) void tmat(
    const float* __restrict__ E2, const float* __restrict__ XL2, float* __restrict__ T)
{
    int b = blockIdx.y, c = blockIdx.x, t = threadIdx.x;
    int d = t & 63, nl = t >> 6;   // nl 0..15
    const float* e = E2 + ((size_t)b * 64 + c) * HW;
    const float* x2 = XL2 + (size_t)b * HW * 64;
    float a0 = 0.f, a1 = 0.f;
    #pragma unroll 4
    for (int k = 0; k < 256; k += 2) {
        int na = k * 16 + nl, nb2 = na + 16;
        a0 += e[na] * x2[(size_t)na * 64 + d];
        a1 += e[nb2] * x2[(size_t)nb2 * 64 + d];
    }
    __shared__ float red[16][64];
    red[nl][d] = a0 + a1;
    __syncthreads();
    if (t < 64) {
        float s = 0.f;
        #pragma unroll
        for (int j = 0; j < 16; j++) s += red[j][t];
        T[((size_t)b * 64 + c) * 64 + t] = s;
    }
}

// softmax over c for each (b, d)
__global__ __launch_bounds__(64) void softT(
    const float* __restrict__ T, float* __restrict__ Ts)
{
    int d = blockIdx.x, b = blockIdx.y, c = threadIdx.x;
    float v = T[((size_t)b * 64 + c) * 64 + d];
    float M = v;
    #pragma unroll
    for (int o = 32; o > 0; o >>= 1) M = fmaxf(M, __shfl_xor(M, o, 64));
    float ez = __expf(v - M);
    float Z = ez;
    #pragma unroll
    for (int o = 32; o > 0; o >>= 1) Z += __shfl_xor(Z, o, 64);
    Ts[((size_t)b * 64 + c) * 64 + d] = ez / Z;
}

// out[b][d][n] = sum_c XMID[b][n][c] * Ts[b][c][d]
__global__ __launch_bounds__(256) void outk(
    const float* __restrict__ XMID, const float* __restrict__ Ts, float* __restrict__ out)
{
    int b = blockIdx.y, n0 = blockIdx.x * 64, t = threadIdx.x;
    __shared__ float Xm[64][65];
    __shared__ float Tl[64][64];
    for (int i = t; i < 4096; i += 256) {
        int nl = i >> 6, c = i & 63;
        Xm[nl][c] = XMID[((size_t)b * HW + n0 + nl) * 64 + c];
    }
    for (int i = t; i < 4096; i += 256) Tl[i >> 6][i & 63] = Ts[(size_t)b * 4096 + i];
    __syncthreads();
    int nl = t & 63, dg = t >> 6;
    float accs[16];
    #pragma unroll
    for (int k = 0; k < 16; k++) accs[k] = 0.f;
    for (int c = 0; c < 64; c++) {
        float xv = Xm[nl][c];
        #pragma unroll
        for (int k = 0; k < 16; k++) accs[k] += xv * Tl[c][dg * 16 + k];
    }
    #pragma unroll
    for (int k = 0; k < 16; k++) {
        int d = dg * 16 + k;
        out[((size_t)b * 64 + d) * HW + n0 + nl] = accs[k];
    }
}

// ---------------------------------------------------------------------------
extern "C" void kernel_launch(void* const* d_in, const int* in_sizes, int n_in,
                              void* d_out, int out_size, void* d_ws, size_t ws_size,
                              hipStream_t stream)
{
    const float* x_latter = (const float*)d_in[0];
    const float* x        = (const float*)d_in[1];
    const float* W_high = (const float*)d_in[2];  const float* b_high = (const float*)d_in[3];
    const float* W_low  = (const float*)d_in[4];  const float* b_low  = (const float*)d_in[5];
    const float* W_val  = (const float*)d_in[6];  const float* b_val  = (const float*)d_in[7];
    const float* W_ec   = (const float*)d_in[8];  const float* b_ec   = (const float*)d_in[9];
    const float* W_mid  = (const float*)d_in[10]; const float* b_mid  = (const float*)d_in[11];
    const float* W_lat  = (const float*)d_in[12]; const float* b_lat  = (const float*)d_in[13];
    float* outp = (float*)d_out;

    const size_t MAT = (size_t)BATCH * CH * HW;  // 1,048,576 elements
    const size_t WFN = (size_t)5 * 8 * 512;      // packed W frags per array

    // ws budget: fixed floats (3 MAT + Zp + T + Ts) + (6 MAT + 2 WFN) shorts + Ep
    const size_t fixed_f = 3 * MAT + (size_t)BATCH * 4 * HW + 2 * (size_t)BATCH * 64 * 64;
    const size_t need8 = (fixed_f + 8 * MAT) * 4 + (6 * MAT + 2 * WFN) * 2;
    int nseg = (ws_size >= need8) ? 8 : 4;

    float* ws = (float*)d_ws;
    size_t off = 0;
    float* XLOW = ws + off; off += MAT;              // [b][n][c]
    float* XMID = ws + off; off += MAT;              // [b][n][c]
    float* XL2  = ws + off; off += MAT;              // [b][n][d]
    float* Zp   = ws + off; off += (size_t)BATCH * 4 * HW;
    float* T    = ws + off; off += (size_t)BATCH * 64 * 64;
    float* Ts   = ws + off; off += (size_t)BATCH * 64 * 64;
    short* sp = (short*)(ws + off);
    short* PAh = sp; sp += MAT;   // packed frags of XLOW (hi)
    short* PAl = sp; sp += MAT;
    short* PBh = sp; sp += MAT;   // packed frags of XLHI (pre-scaled by LOG2E)
    short* PBl = sp; sp += MAT;
    short* PVh = sp; sp += MAT;   // packed B-frags of V (sigma-permuted k)
    short* PVl = sp; sp += MAT;
    short* WFh = sp; sp += WFN;   // packed W A-frags (5 modes)
    short* WFl = sp; sp += WFN;
    float* Ep  = (float*)sp;      // nseg m-segment partials of E (last region)
    float* E2  = (float*)PAh;     // alias: PA dead after epass10

    wpack<<<dim3(5), 256, 0, stream>>>(W_low, W_val, W_mid, W_lat, W_high, WFh, WFl);
    convm<<<dim3(64, BATCH, 5), 256, 0, stream>>>(
        x, x_latter, WFh, WFl, b_low, b_val, b_mid, b_lat, b_high,
        XLOW, XMID, XL2, PAh, PAl, PBh, PBl, PVh, PVl);
    zpass2<<<dim3(1024), 256, 0, stream>>>(PAh, PAl, PBh, PBl, Zp);
    epass10<<<dim3(32 * nseg * 4), 256, 0, stream>>>(
        PAh, PAl, PBh, PBl, PVh, PVl, Zp, Ep, nseg);
    if (nseg == 8)
        econv6<8><<<dim3(64, BATCH), 256, 0, stream>>>(Ep, XLOW, W_ec, b_ec, E2);
    else
        econv6<4><<<dim3(64, BATCH), 256, 0, stream>>>(Ep, XLOW, W_ec, b_ec, E2);
    tmat<<<dim3(64, BATCH), 1024, 0, stream>>>(E2, XL2, T);
    softT<<<dim3(64, BATCH), 64, 0, stream>>>(T, Ts);
    outk<<<dim3(64, BATCH), 256, 0, stream>>>(XMID, Ts, outp);
}